// Round 1
// baseline (591.897 us; speedup 1.0000x reference)
//
#include <hip/hip_runtime.h>
#include <hip/hip_bf16.h>
#include <stdint.h>

typedef __attribute__((ext_vector_type(8))) short short8;
typedef __attribute__((ext_vector_type(4))) float float4v;

__device__ __forceinline__ float bf2f(uint16_t u) {
    union { uint32_t i; float f; } v; v.i = ((uint32_t)u) << 16; return v.f;
}
__device__ __forceinline__ uint16_t f2bf(float f) {  // round-to-nearest-even
    union { float f; uint32_t i; } v; v.f = f;
    uint32_t x = v.i;
    uint32_t r = (x + 0x7fffu + ((x >> 16) & 1u)) >> 16;
    return (uint16_t)r;
}
// NaN-PROPAGATING relu: exact for normal x; NaN stays NaN (diagnostic).
__device__ __forceinline__ float relu_nanprop(float x) {
    return 0.5f * (x + fabsf(x));
}

// ---------------------------------------------------------------------------
// Kernel 1 (fp32 in): A1T[n][f] = sum_d W1[f][d]*Wm1[d][n]  (bf16 out, [64][1024])
//                     A2T likewise with Wm1 rows 128..255.
//                     tbias[n] = b1@Wm1_top + b2@Wm1_bot + bm1  (fp32)
// Remapped: lane = n (0..63), wave-uniform f-row -> W reads are scalar
// (wave-uniform), wm reads are 256B coalesced. Output writes are 2B scatter
// but total output is only 256 KB.
// ---------------------------------------------------------------------------
__global__ __launch_bounds__(256) void precompute_kernel(
    const float* __restrict__ W1, const float* __restrict__ W2,
    const float* __restrict__ Wm1,
    const float* __restrict__ b1, const float* __restrict__ b2,
    const float* __restrict__ bm1,
    uint16_t* __restrict__ A1T, uint16_t* __restrict__ A2T,
    float* __restrict__ tbias)
{
    int b = blockIdx.x, t = threadIdx.x;
    if (b < 512) {
        int g   = b * 4 + (t >> 6);    // f-row id over both matrices, 0..2047
        int mat = g >> 10;             // 0: gene, 1: cell
        int f   = g & 1023;
        int n   = t & 63;
        const float* W    = mat ? W2 : W1;
        const float* wm   = Wm1 + mat * 128 * 64;
        const float* Wrow = W + (size_t)f * 128;
        float acc = 0.f;
        #pragma unroll 8
        for (int d = 0; d < 128; ++d)
            acc = fmaf(Wrow[d], wm[d * 64 + n], acc);
        (mat ? A2T : A1T)[(size_t)n * 1024 + f] = f2bf(acc);
    } else if (t < 64) {
        float acc = bm1[t];
        for (int d = 0; d < 128; ++d) acc += b1[d] * Wm1[d * 64 + t];
        for (int d = 0; d < 128; ++d) acc += b2[d] * Wm1[(128 + d) * 64 + t];
        tbias[t] = acc;
    }
}

// ---------------------------------------------------------------------------
// Kernel 2: G(bf16 [M][64]) = X(fp32 [M][1024]) @ B, B stored transposed
// (BT = A?T bf16 [64][1024]).
//
// Rewritten barrier-free: NO LDS, no __syncthreads. Each wave independently
// owns 16 output rows; 4 waves/block => BM=64, grid 2x782 blocks
// (6.1 waves/SIMD vs 3.05 before). A-fragments load directly from global:
// lane (m=lane&15, q=lane>>4) reads X[row=base+m][32*p + q*8 .. +8) fp32
// (wave = 16 rows x 128B contiguous segments, every byte used exactly once),
// packs to bf16 in-register. B-fragments from the L2-hot 128KB BT.
// Explicit SW pipeline, all register indices compile-time (full unroll):
//   A prefetch depth 2 (covers ~900cy HBM latency),
//   B prefetch depth 1 (covers ~200cy L2 latency).
// p = kk*2+s in [0,32): one 16x16x32 K-slice per p, k_local = q*8+j.
// ---------------------------------------------------------------------------
__global__ __launch_bounds__(256, 4) void gemm64_kernel(
    const float* __restrict__ X1, const float* __restrict__ X2,
    const uint16_t* __restrict__ A1T, const uint16_t* __restrict__ A2T,
    uint16_t* __restrict__ G1, uint16_t* __restrict__ G2, int M1, int M2)
{
    const int which = blockIdx.y;
    const float* __restrict__ X     = which ? X2  : X1;
    const uint16_t* __restrict__ BT = which ? A2T : A1T;
    uint16_t* __restrict__ G        = which ? G2  : G1;
    const int M = which ? M2 : M1;

    const int t    = threadIdx.x;
    const int wid  = t >> 6;
    const int lane = t & 63;
    const int m    = lane & 15;
    const int q    = lane >> 4;

    const int rowBase = blockIdx.x * 64 + wid * 16;   // wave-uniform
    if (rowBase >= M) return;
    int lrow = rowBase + m;
    if (lrow >= M) lrow = M - 1;                      // clamped loads, guarded stores

    const float*    Xb = X  + (size_t)lrow * 1024 + q * 8;
    const uint16_t* Bb = BT + (size_t)m * 1024 + q * 8;   // + nt*16*1024 + 32*p

    float4v acc[4];
    #pragma unroll
    for (int nt = 0; nt < 4; ++nt) acc[nt] = (float4v){0.f, 0.f, 0.f, 0.f};

    // ---- prologue: A for p=0,1 ; B for p=0 ----
    float4 pa0[2], pa1[2];
    pa0[0] = *(const float4*)(Xb + 0);
    pa1[0] = *(const float4*)(Xb + 4);
    pa0[1] = *(const float4*)(Xb + 32);
    pa1[1] = *(const float4*)(Xb + 36);
    short8 pb0 = *(const short8*)(Bb + 0 * 16384);
    short8 pb1 = *(const short8*)(Bb + 1 * 16384);
    short8 pb2 = *(const short8*)(Bb + 2 * 16384);
    short8 pb3 = *(const short8*)(Bb + 3 * 16384);

    #pragma unroll
    for (int p = 0; p < 32; ++p) {
        float4 a0 = pa0[p & 1], a1 = pa1[p & 1];      // p&1 is compile-time
        const int np = (p + 2 < 32) ? p + 2 : p;      // tail: harmless reload
        pa0[p & 1] = *(const float4*)(Xb + 32 * np);
        pa1[p & 1] = *(const float4*)(Xb + 32 * np + 4);

        short8 b0 = pb0, b1 = pb1, b2 = pb2, b3 = pb3;
        const int bp = (p + 1 < 32) ? p + 1 : p;
        pb0 = *(const short8*)(Bb + 0 * 16384 + 32 * bp);
        pb1 = *(const short8*)(Bb + 1 * 16384 + 32 * bp);
        pb2 = *(const short8*)(Bb + 2 * 16384 + 32 * bp);
        pb3 = *(const short8*)(Bb + 3 * 16384 + 32 * bp);

        union { short8 s8; uint32_t u[4]; } P;
        P.u[0] = (uint32_t)f2bf(a0.x) | ((uint32_t)f2bf(a0.y) << 16);
        P.u[1] = (uint32_t)f2bf(a0.z) | ((uint32_t)f2bf(a0.w) << 16);
        P.u[2] = (uint32_t)f2bf(a1.x) | ((uint32_t)f2bf(a1.y) << 16);
        P.u[3] = (uint32_t)f2bf(a1.z) | ((uint32_t)f2bf(a1.w) << 16);

        acc[0] = __builtin_amdgcn_mfma_f32_16x16x32_bf16(P.s8, b0, acc[0], 0, 0, 0);
        acc[1] = __builtin_amdgcn_mfma_f32_16x16x32_bf16(P.s8, b1, acc[1], 0, 0, 0);
        acc[2] = __builtin_amdgcn_mfma_f32_16x16x32_bf16(P.s8, b2, acc[2], 0, 0, 0);
        acc[3] = __builtin_amdgcn_mfma_f32_16x16x32_bf16(P.s8, b3, acc[3], 0, 0, 0);
    }

    // epilogue: C/D layout col = lane&15, row = q*4 + reg   [m89/m91 verified]
    #pragma unroll
    for (int reg = 0; reg < 4; ++reg) {
        int grow = rowBase + q * 4 + reg;
        if (grow < M) {
            #pragma unroll
            for (int nt = 0; nt < 4; ++nt)
                G[(size_t)grow * 64 + nt * 16 + m] = f2bf(acc[nt][reg]);
        }
    }
}

// ---------------------------------------------------------------------------
// Kernel 3: per-edge MLP.  t = relu(g1[src]+g2[dst]+tbias) ; u = t@Wm2+bm2 ;
//           pred = relu(u)@Wm3 + bm3.  One thread per edge, fp32 out.
// Depth-1 prefetch of the two 16B gather chunks: next chunk is in flight
// under the current 256-FMA block (gathers are random in a 12.8MB table).
// ---------------------------------------------------------------------------
__global__ __launch_bounds__(256) void edge_mlp_kernel(
    const uint16_t* __restrict__ g1, const uint16_t* __restrict__ g2,
    const float* __restrict__ tbias, const int* __restrict__ eidx,
    const float* __restrict__ Wm2, const float* __restrict__ bm2,
    const float* __restrict__ Wm3, const float* __restrict__ bm3,
    float* __restrict__ out, int E)
{
    int e = blockIdx.x * 256 + threadIdx.x;
    if (e >= E) e = E - 1;                 // clamp: uniform control flow
    int src = eidx[e];
    int dst = eidx[E + e];
    const uint4* r1 = (const uint4*)(g1 + (size_t)src * 64);
    const uint4* r2 = (const uint4*)(g2 + (size_t)dst * 64);

    float u[32];
    #pragma unroll
    for (int j = 0; j < 32; ++j) u[j] = bm2[j];

    uint4 a = r1[0], b = r2[0];

    #pragma unroll
    for (int c = 0; c < 8; ++c) {
        const int nc = (c + 1 < 8) ? c + 1 : 7;
        uint4 na = r1[nc], nb = r2[nc];    // issued before the FMA block

        uint32_t aw[4] = { a.x, a.y, a.z, a.w };
        uint32_t bw[4] = { b.x, b.y, b.z, b.w };
        float tv[8];
        #pragma unroll
        for (int h = 0; h < 4; ++h) {
            float alo, ahi, blo, bhi;
            { union { uint32_t i; float f; } v; v.i = aw[h] << 16;        alo = v.f; }
            { union { uint32_t i; float f; } v; v.i = aw[h] & 0xffff0000u; ahi = v.f; }
            { union { uint32_t i; float f; } v; v.i = bw[h] << 16;        blo = v.f; }
            { union { uint32_t i; float f; } v; v.i = bw[h] & 0xffff0000u; bhi = v.f; }
            tv[2 * h]     = relu_nanprop(alo + blo + tbias[c * 8 + 2 * h]);
            tv[2 * h + 1] = relu_nanprop(ahi + bhi + tbias[c * 8 + 2 * h + 1]);
        }
        #pragma unroll
        for (int i = 0; i < 8; ++i) {
            const float* wrow = Wm2 + (c * 8 + i) * 32;
            #pragma unroll
            for (int j = 0; j < 32; ++j)
                u[j] = fmaf(tv[i], wrow[j], u[j]);
        }
        a = na; b = nb;
    }

    float p = bm3[0];
    #pragma unroll
    for (int j = 0; j < 32; ++j)
        p += relu_nanprop(u[j]) * Wm3[j];
    out[e] = p;
}

// ---------------------------------------------------------------------------
extern "C" void kernel_launch(void* const* d_in, const int* in_sizes, int n_in,
                              void* d_out, int out_size, void* d_ws, size_t ws_size,
                              hipStream_t stream) {
    const float* x_gene = (const float*)d_in[0];
    const float* x_cell = (const float*)d_in[1];
    const int*   eidx   = (const int*)d_in[2];
    const float* W1  = (const float*)d_in[3];
    const float* b1  = (const float*)d_in[4];
    const float* W2  = (const float*)d_in[5];
    const float* b2  = (const float*)d_in[6];
    const float* Wm1 = (const float*)d_in[7];
    const float* bm1 = (const float*)d_in[8];
    const float* Wm2 = (const float*)d_in[9];
    const float* bm2 = (const float*)d_in[10];
    const float* Wm3 = (const float*)d_in[11];
    const float* bm3 = (const float*)d_in[12];

    const int M1 = in_sizes[0] / 1024;
    const int M2 = in_sizes[1] / 1024;
    const int E  = in_sizes[2] / 2;

    uint8_t* ws = (uint8_t*)d_ws;
    uint16_t* A1T   = (uint16_t*)(ws + 0);          // 131072 B
    uint16_t* A2T   = (uint16_t*)(ws + 131072);     // 131072 B
    float*    tbias = (float*)(ws + 262144);        //   256 B
    uint16_t* G1    = (uint16_t*)(ws + 524288);
    size_t g1_bytes = ((size_t)M1 * 64 * 2 + 127) & ~(size_t)127;
    uint16_t* G2    = (uint16_t*)(ws + 524288 + g1_bytes);

    precompute_kernel<<<513, 256, 0, stream>>>(
        W1, W2, Wm1, b1, b2, bm1, A1T, A2T, tbias);

    int Mmax = M1 > M2 ? M1 : M2;
    dim3 ggrid((Mmax + 63) / 64, 2);
    gemm64_kernel<<<ggrid, 256, 0, stream>>>(x_gene, x_cell, A1T, A2T, G1, G2, M1, M2);

    edge_mlp_kernel<<<(E + 255) / 256, 256, 0, stream>>>(
        G1, G2, tbias, eidx, Wm2, bm2, Wm3, bm3, (float*)d_out, E);
}

// Round 2
// 543.631 us; speedup vs baseline: 1.0888x; 1.0888x over previous
//
#include <hip/hip_runtime.h>
#include <hip/hip_bf16.h>
#include <stdint.h>

typedef __attribute__((ext_vector_type(8))) short short8;
typedef __attribute__((ext_vector_type(4))) float float4v;

__device__ __forceinline__ float bf2f(uint16_t u) {
    union { uint32_t i; float f; } v; v.i = ((uint32_t)u) << 16; return v.f;
}
__device__ __forceinline__ uint16_t f2bf(float f) {  // round-to-nearest-even
    union { float f; uint32_t i; } v; v.f = f;
    uint32_t x = v.i;
    uint32_t r = (x + 0x7fffu + ((x >> 16) & 1u)) >> 16;
    return (uint16_t)r;
}

// ---------------------------------------------------------------------------
// Kernel 1 (fp32 in): A1T[n][f] = sum_d W1[f][d]*Wm1[d][n]  (bf16 out, [64][1024])
//                     A2T likewise with Wm1 rows 128..255.
//                     tbias[n] = b1@Wm1_top + b2@Wm1_bot + bm1  (fp32)
//                     Wm2bfT[n][k] = bf16(Wm2[k][n])  ([32][64] bf16, for MFMA B)
// ---------------------------------------------------------------------------
__global__ __launch_bounds__(256) void precompute_kernel(
    const float* __restrict__ W1, const float* __restrict__ W2,
    const float* __restrict__ Wm1, const float* __restrict__ Wm2,
    const float* __restrict__ b1, const float* __restrict__ b2,
    const float* __restrict__ bm1,
    uint16_t* __restrict__ A1T, uint16_t* __restrict__ A2T,
    float* __restrict__ tbias, uint16_t* __restrict__ Wm2bfT)
{
    int b = blockIdx.x, t = threadIdx.x;
    if (b < 512) {
        int g   = b * 4 + (t >> 6);    // f-row id over both matrices, 0..2047
        int mat = g >> 10;             // 0: gene, 1: cell
        int f   = g & 1023;
        int n   = t & 63;
        const float* W    = mat ? W2 : W1;
        const float* wm   = Wm1 + mat * 128 * 64;
        const float* Wrow = W + (size_t)f * 128;
        float acc = 0.f;
        #pragma unroll 8
        for (int d = 0; d < 128; ++d)
            acc = fmaf(Wrow[d], wm[d * 64 + n], acc);
        (mat ? A2T : A1T)[(size_t)n * 1024 + f] = f2bf(acc);
    } else {
        // Wm2 transpose+convert: thread t -> n = t>>3, k = (t&7)*8 .. +8
        int n  = t >> 3;
        int k0 = (t & 7) * 8;
        #pragma unroll
        for (int i = 0; i < 8; ++i)
            Wm2bfT[n * 64 + k0 + i] = f2bf(Wm2[(size_t)(k0 + i) * 32 + n]);
        if (t < 64) {
            float acc = bm1[t];
            for (int d = 0; d < 128; ++d) acc += b1[d] * Wm1[d * 64 + t];
            for (int d = 0; d < 128; ++d) acc += b2[d] * Wm1[(128 + d) * 64 + t];
            tbias[t] = acc;
        }
    }
}

// ---------------------------------------------------------------------------
// Kernel 2: G(bf16 [M][64]) = X(fp32 [M][1024]) @ B, B stored transposed
// (BT = A?T bf16 [64][1024]).  BM=64, BK=128, 256 thr (4 waves), each wave
// owns 16 output rows.  Round-0 proven structure (batched global->reg->pack->
// LDS with barriers so the compiler can't sink loads), but grid is 2x1564
// blocks (6.1 blocks/CU, was grid-limited at 3.05) and 8 barrier-drain
// events/block (was 16).  Chunk XOR swizzle (chunk=8 bf16=16B; phys chunk pc
// of row r holds logical chunk pc^(r&7)): stores linear/conflict-free,
// fragment reads b128 (round-0 measured 0 bank conflicts with this family).
// ---------------------------------------------------------------------------
__global__ __launch_bounds__(256) void gemm64_kernel(
    const float* __restrict__ X1, const float* __restrict__ X2,
    const uint16_t* __restrict__ A1T, const uint16_t* __restrict__ A2T,
    uint16_t* __restrict__ G1, uint16_t* __restrict__ G2, int M1, int M2)
{
    const int which = blockIdx.y;
    const float* __restrict__ X     = which ? X2  : X1;
    const uint16_t* __restrict__ BT = which ? A2T : A1T;
    uint16_t* __restrict__ G        = which ? G2  : G1;
    const int M = which ? M2 : M1;

    const int blockRow = blockIdx.x * 64;
    if (blockRow >= M) return;

    __shared__ uint16_t As[64 * 128];   // 16 KB

    const int t    = threadIdx.x;
    const int wid  = t >> 6;
    const int lane = t & 63;
    const int m    = lane & 15;
    const int q    = lane >> 4;

    float4v acc[4];
    #pragma unroll
    for (int nt = 0; nt < 4; ++nt) acc[nt] = (float4v){0.f, 0.f, 0.f, 0.f};

    for (int kk = 0; kk < 8; ++kk) {
        // ---- load A tile (fp32) into registers, 8 floats per chunk ----
        float4 av0[4], av1[4];
        int    dstc[4];
        #pragma unroll
        for (int it = 0; it < 4; ++it) {
            int c   = it * 256 + t;        // chunk id 0..1023
            int row = c >> 4, pc = c & 15;
            int lc  = pc ^ (row & 7);      // logical chunk stored at pc
            int grow = blockRow + row; if (grow >= M) grow = M - 1;
            const float4* src = (const float4*)(X + (size_t)grow * 1024 + kk * 128 + lc * 8);
            av0[it] = src[0];
            av1[it] = src[1];
            dstc[it] = c * 8;
        }
        __syncthreads();                   // previous iter's readers done
        #pragma unroll
        for (int it = 0; it < 4; ++it) {
            uint4 pk;
            pk.x = (uint32_t)f2bf(av0[it].x) | ((uint32_t)f2bf(av0[it].y) << 16);
            pk.y = (uint32_t)f2bf(av0[it].z) | ((uint32_t)f2bf(av0[it].w) << 16);
            pk.z = (uint32_t)f2bf(av1[it].x) | ((uint32_t)f2bf(av1[it].y) << 16);
            pk.w = (uint32_t)f2bf(av1[it].z) | ((uint32_t)f2bf(av1[it].w) << 16);
            *(uint4*)(As + dstc[it]) = pk;
        }
        __syncthreads();                   // A tile visible

        #pragma unroll
        for (int p = 0; p < 4; ++p) {
            short8 af, bfr[4];
            int row = wid * 16 + m;
            int pc  = (p * 4 + q) ^ (row & 7);
            af = *(const short8*)(As + row * 128 + pc * 8);
            #pragma unroll
            for (int nt = 0; nt < 4; ++nt) {
                int n = nt * 16 + m;
                // B[k = p*32+q*8+j][n] == BT[n][kk*128 + (p*4+q)*8 + j]
                bfr[nt] = *(const short8*)(BT + (size_t)n * 1024 + kk * 128 + (p * 4 + q) * 8);
            }
            #pragma unroll
            for (int nt = 0; nt < 4; ++nt)
                acc[nt] = __builtin_amdgcn_mfma_f32_16x16x32_bf16(
                    af, bfr[nt], acc[nt], 0, 0, 0);
        }
    }

    // epilogue: C/D layout col = lane&15, row = q*4 + reg   [m89/m91 verified]
    #pragma unroll
    for (int reg = 0; reg < 4; ++reg) {
        int grow = blockRow + wid * 16 + q * 4 + reg;
        if (grow < M) {
            #pragma unroll
            for (int nt = 0; nt < 4; ++nt)
                G[(size_t)grow * 64 + nt * 16 + m] = f2bf(acc[nt][reg]);
        }
    }
}

// ---------------------------------------------------------------------------
// Kernel 3: per-edge MLP, MFMA version.
//   t[64] = relu(g1[src]+g2[dst]+tbias)  -> bf16, staged in LDS (256 edges)
//   U[256][32] = T @ Wm2   via mfma_f32_16x16x32_bf16 (fp32 accum)
//   pred = relu(U + bm2) @ Wm3 + bm3     via 16-lane shfl_xor reduce
// One wave owns 64 edges (4 M-subtiles x 2 N-tiles x K=64 -> 16 MFMAs).
// LDS tile chunk-XOR swizzled (phys chunk = c ^ (row&7)) so the per-row
// b128 stores and the fragment b128 reads both spread across bank groups.
// ---------------------------------------------------------------------------
__global__ __launch_bounds__(256) void edge_mlp_kernel(
    const uint16_t* __restrict__ g1, const uint16_t* __restrict__ g2,
    const float* __restrict__ tbias, const int* __restrict__ eidx,
    const uint16_t* __restrict__ Wm2bfT, const float* __restrict__ bm2,
    const float* __restrict__ Wm3, const float* __restrict__ bm3,
    float* __restrict__ out, int E)
{
    __shared__ uint16_t T[256 * 64];   // 32 KB

    const int t    = threadIdx.x;
    const int wid  = t >> 6;
    const int lane = t & 63;
    const int m    = lane & 15;
    const int q    = lane >> 4;

    // B fragments (once per block, 4KB L2-hot): B[k][n] = Wm2bfT[n][k]
    short8 bfrag[2][2];
    #pragma unroll
    for (int s = 0; s < 2; ++s)
        #pragma unroll
        for (int nt = 0; nt < 2; ++nt)
            bfrag[s][nt] = *(const short8*)(Wm2bfT + (nt * 16 + m) * 64 + s * 32 + q * 8);

    const float bm2a = bm2[m],      bm2b = bm2[16 + m];
    const float w3a  = Wm3[m],      w3b  = Wm3[16 + m];
    const float b3   = bm3[0];

    const int tileBase = blockIdx.x * 256;
    int e = tileBase + t; if (e >= E) e = E - 1;   // clamp; stores guarded below
    const int src = eidx[e];
    const int dst = eidx[E + e];
    const uint4* r1 = (const uint4*)(g1 + (size_t)src * 64);
    const uint4* r2 = (const uint4*)(g2 + (size_t)dst * 64);

    // gather both 128B rows with full ILP (16 loads in flight)
    uint4 A[8], B[8];
    #pragma unroll
    for (int c = 0; c < 8; ++c) { A[c] = r1[c]; B[c] = r2[c]; }

    // t = relu(a+b+tbias), pack bf16, store row t (swizzled chunks)
    #pragma unroll
    for (int c = 0; c < 8; ++c) {
        uint32_t aw[4] = { A[c].x, A[c].y, A[c].z, A[c].w };
        uint32_t bw[4] = { B[c].x, B[c].y, B[c].z, B[c].w };
        uint32_t pw[4];
        #pragma unroll
        for (int h = 0; h < 4; ++h) {
            float alo, ahi, blo, bhi;
            { union { uint32_t i; float f; } v; v.i = aw[h] << 16;        alo = v.f; }
            { union { uint32_t i; float f; } v; v.i = aw[h] & 0xffff0000u; ahi = v.f; }
            { union { uint32_t i; float f; } v; v.i = bw[h] << 16;        blo = v.f; }
            { union { uint32_t i; float f; } v; v.i = bw[h] & 0xffff0000u; bhi = v.f; }
            float t0 = fmaxf(alo + blo + tbias[c * 8 + 2 * h],     0.f);
            float t1 = fmaxf(ahi + bhi + tbias[c * 8 + 2 * h + 1], 0.f);
            pw[h] = (uint32_t)f2bf(t0) | ((uint32_t)f2bf(t1) << 16);
        }
        uint4 pk; pk.x = pw[0]; pk.y = pw[1]; pk.z = pw[2]; pk.w = pw[3];
        int pc = c ^ (t & 7);
        *(uint4*)(T + t * 64 + pc * 8) = pk;
    }
    __syncthreads();

    // wave wid owns T rows wid*64 .. wid*64+63
    float4v acc[4][2];
    #pragma unroll
    for (int r = 0; r < 4; ++r) {
        acc[r][0] = (float4v){0.f, 0.f, 0.f, 0.f};
        acc[r][1] = (float4v){0.f, 0.f, 0.f, 0.f};
    }
    #pragma unroll
    for (int r = 0; r < 4; ++r) {
        const int row = wid * 64 + r * 16 + m;
        #pragma unroll
        for (int s = 0; s < 2; ++s) {
            const int pc = (s * 4 + q) ^ (row & 7);
            short8 af = *(const short8*)(T + row * 64 + pc * 8);
            acc[r][0] = __builtin_amdgcn_mfma_f32_16x16x32_bf16(af, bfrag[s][0], acc[r][0], 0, 0, 0);
            acc[r][1] = __builtin_amdgcn_mfma_f32_16x16x32_bf16(af, bfrag[s][1], acc[r][1], 0, 0, 0);
        }
    }

    // layer 3: per edge, lane holds u[col m] (nt=0) and u[col 16+m] (nt=1);
    // 16-lane butterfly sum within each q-group.  C/D row = q*4+reg.
    #pragma unroll
    for (int r = 0; r < 4; ++r) {
        #pragma unroll
        for (int reg = 0; reg < 4; ++reg) {
            float v0 = fmaxf(acc[r][0][reg] + bm2a, 0.f);
            float v1 = fmaxf(acc[r][1][reg] + bm2b, 0.f);
            float p  = fmaf(v0, w3a, v1 * w3b);
            p += __shfl_xor(p, 1);
            p += __shfl_xor(p, 2);
            p += __shfl_xor(p, 4);
            p += __shfl_xor(p, 8);
            int eo = tileBase + wid * 64 + r * 16 + q * 4 + reg;
            if (m == 0 && eo < E) out[eo] = p + b3;
        }
    }
}

// ---------------------------------------------------------------------------
extern "C" void kernel_launch(void* const* d_in, const int* in_sizes, int n_in,
                              void* d_out, int out_size, void* d_ws, size_t ws_size,
                              hipStream_t stream) {
    const float* x_gene = (const float*)d_in[0];
    const float* x_cell = (const float*)d_in[1];
    const int*   eidx   = (const int*)d_in[2];
    const float* W1  = (const float*)d_in[3];
    const float* b1  = (const float*)d_in[4];
    const float* W2  = (const float*)d_in[5];
    const float* b2  = (const float*)d_in[6];
    const float* Wm1 = (const float*)d_in[7];
    const float* bm1 = (const float*)d_in[8];
    const float* Wm2 = (const float*)d_in[9];
    const float* bm2 = (const float*)d_in[10];
    const float* Wm3 = (const float*)d_in[11];
    const float* bm3 = (const float*)d_in[12];

    const int M1 = in_sizes[0] / 1024;
    const int M2 = in_sizes[1] / 1024;
    const int E  = in_sizes[2] / 2;

    uint8_t* ws = (uint8_t*)d_ws;
    uint16_t* A1T    = (uint16_t*)(ws + 0);          // 131072 B
    uint16_t* A2T    = (uint16_t*)(ws + 131072);     // 131072 B
    float*    tbias  = (float*)(ws + 262144);        //   256 B
    uint16_t* Wm2bfT = (uint16_t*)(ws + 262400);     //  4096 B
    uint16_t* G1     = (uint16_t*)(ws + 524288);
    size_t g1_bytes  = ((size_t)M1 * 64 * 2 + 127) & ~(size_t)127;
    uint16_t* G2     = (uint16_t*)(ws + 524288 + g1_bytes);

    precompute_kernel<<<513, 256, 0, stream>>>(
        W1, W2, Wm1, Wm2, b1, b2, bm1, A1T, A2T, tbias, Wm2bfT);

    int Mmax = M1 > M2 ? M1 : M2;
    dim3 ggrid((Mmax + 63) / 64, 2);
    gemm64_kernel<<<ggrid, 256, 0, stream>>>(x_gene, x_cell, A1T, A2T, G1, G2, M1, M2);

    edge_mlp_kernel<<<(E + 255) / 256, 256, 0, stream>>>(
        G1, G2, tbias, eidx, Wm2bfT, bm2, Wm3, bm3, (float*)d_out, E);
}

// Round 3
// 531.076 us; speedup vs baseline: 1.1145x; 1.0236x over previous
//
#include <hip/hip_runtime.h>
#include <hip/hip_bf16.h>
#include <stdint.h>

typedef __attribute__((ext_vector_type(8))) short short8;
typedef __attribute__((ext_vector_type(4))) float float4v;

typedef const __attribute__((address_space(1))) uint32_t* gas_ptr;
typedef __attribute__((address_space(3))) uint32_t*       las_ptr;

__device__ __forceinline__ uint16_t f2bf(float f) {  // round-to-nearest-even
    union { float f; uint32_t i; } v; v.f = f;
    uint32_t x = v.i;
    uint32_t r = (x + 0x7fffu + ((x >> 16) & 1u)) >> 16;
    return (uint16_t)r;
}

// ---------------------------------------------------------------------------
// Kernel 1 (fp32 in): A1T[n][f] = sum_d W1[f][d]*Wm1[d][n]  (bf16 out, [64][1024])
//                     A2T likewise with Wm1 rows 128..255.
//                     tbias[n] = b1@Wm1_top + b2@Wm1_bot + bm1  (fp32)
//                     Wm2bfT[n][k] = bf16(Wm2[k][n])  ([32][64] bf16, for MFMA B)
// ---------------------------------------------------------------------------
__global__ __launch_bounds__(256) void precompute_kernel(
    const float* __restrict__ W1, const float* __restrict__ W2,
    const float* __restrict__ Wm1, const float* __restrict__ Wm2,
    const float* __restrict__ b1, const float* __restrict__ b2,
    const float* __restrict__ bm1,
    uint16_t* __restrict__ A1T, uint16_t* __restrict__ A2T,
    float* __restrict__ tbias, uint16_t* __restrict__ Wm2bfT)
{
    int b = blockIdx.x, t = threadIdx.x;
    if (b < 512) {
        int g   = b * 4 + (t >> 6);    // f-row id over both matrices, 0..2047
        int mat = g >> 10;             // 0: gene, 1: cell
        int f   = g & 1023;
        int n   = t & 63;
        const float* W    = mat ? W2 : W1;
        const float* wm   = Wm1 + mat * 128 * 64;
        const float* Wrow = W + (size_t)f * 128;
        float acc = 0.f;
        #pragma unroll 8
        for (int d = 0; d < 128; ++d)
            acc = fmaf(Wrow[d], wm[d * 64 + n], acc);
        (mat ? A2T : A1T)[(size_t)n * 1024 + f] = f2bf(acc);
    } else {
        // Wm2 transpose+convert: thread t -> n = t>>3, k = (t&7)*8 .. +8
        int n  = t >> 3;
        int k0 = (t & 7) * 8;
        #pragma unroll
        for (int i = 0; i < 8; ++i)
            Wm2bfT[n * 64 + k0 + i] = f2bf(Wm2[(size_t)(k0 + i) * 32 + n]);
        if (t < 64) {
            float acc = bm1[t];
            for (int d = 0; d < 128; ++d) acc += b1[d] * Wm1[d * 64 + t];
            for (int d = 0; d < 128; ++d) acc += b2[d] * Wm1[(128 + d) * 64 + t];
            tbias[t] = acc;
        }
    }
}

// ---------------------------------------------------------------------------
// Kernel 2: G(bf16 [M][64]) = X(fp32 [M][1024]) @ B, BT = A?T bf16 [64][1024].
// BM=64, BK=64 fp32 tile (16 KB), 3-deep LDS ring (48 KB), 4 waves.
// T3+T4 structure: global_load_lds(16B) staging + raw s_barrier + COUNTED
// s_waitcnt vmcnt(N) (never 0 mid-loop) so tiles i+1,i+2 stay in flight
// across barriers.  X stays fp32 in LDS; bf16 pack happens at fragment-read.
// Swizzle: LDS dest linear (gload_lds requirement, m104); the 16B halfunit
// hu of row r holds logical halfunit hu^(r&15), applied by pre-swizzling the
// GLOBAL source column (m173).  Fragment reads: 2x ds_read_b128 per K-slice,
// independent addresses, conflict-free (each 16-lane phase hits all 16
// halfunit slots exactly once).
// ---------------------------------------------------------------------------
__global__ __launch_bounds__(256, 3) void gemm64_kernel(
    const float* __restrict__ X1, const float* __restrict__ X2,
    const uint16_t* __restrict__ A1T, const uint16_t* __restrict__ A2T,
    uint16_t* __restrict__ G1, uint16_t* __restrict__ G2, int M1, int M2)
{
    const int which = blockIdx.y;
    const float* __restrict__ X     = which ? X2  : X1;
    const uint16_t* __restrict__ BT = which ? A2T : A1T;
    uint16_t* __restrict__ G        = which ? G2  : G1;
    const int M = which ? M2 : M1;

    const int blockRow = blockIdx.x * 64;
    if (blockRow >= M) return;

    __shared__ __align__(16) float As[3 * 64 * 64];   // 48 KB

    const int t    = threadIdx.x;
    const int wid  = t >> 6;
    const int lane = t & 63;
    const int m    = lane & 15;
    const int q    = lane >> 4;
    const int sblk = wid * 4;            // this wave's first 1KB staging block

    // Per-lane global staging addresses (row/col fixed; tile adds i*64).
    // Issue j: LDS bytes [(sblk+j)*1024 + lane*16): row = (sblk+j)*4 + lane>>4,
    // halfunit hu = lane&15 -> logical halfunit lu = hu ^ (row&15).
    const float *sa0, *sa1, *sa2, *sa3;
    {
        int r0 = (sblk + 0) * 4 + (lane >> 4);
        int r1 = (sblk + 1) * 4 + (lane >> 4);
        int r2 = (sblk + 2) * 4 + (lane >> 4);
        int r3 = (sblk + 3) * 4 + (lane >> 4);
        int g0 = blockRow + r0; if (g0 >= M) g0 = M - 1;
        int g1 = blockRow + r1; if (g1 >= M) g1 = M - 1;
        int g2 = blockRow + r2; if (g2 >= M) g2 = M - 1;
        int g3 = blockRow + r3; if (g3 >= M) g3 = M - 1;
        sa0 = X + (size_t)g0 * 1024 + (((lane & 15) ^ (r0 & 15)) * 4);
        sa1 = X + (size_t)g1 * 1024 + (((lane & 15) ^ (r1 & 15)) * 4);
        sa2 = X + (size_t)g2 * 1024 + (((lane & 15) ^ (r2 & 15)) * 4);
        sa3 = X + (size_t)g3 * 1024 + (((lane & 15) ^ (r3 & 15)) * 4);
    }

#define STAGE(ii, tb)                                                          \
    do {                                                                       \
        __builtin_amdgcn_global_load_lds((gas_ptr)(sa0 + (ii) * 64),           \
            (las_ptr)((tb) + (sblk + 0) * 256), 16, 0, 0);                     \
        __builtin_amdgcn_global_load_lds((gas_ptr)(sa1 + (ii) * 64),           \
            (las_ptr)((tb) + (sblk + 1) * 256), 16, 0, 0);                     \
        __builtin_amdgcn_global_load_lds((gas_ptr)(sa2 + (ii) * 64),           \
            (las_ptr)((tb) + (sblk + 2) * 256), 16, 0, 0);                     \
        __builtin_amdgcn_global_load_lds((gas_ptr)(sa3 + (ii) * 64),           \
            (las_ptr)((tb) + (sblk + 3) * 256), 16, 0, 0);                     \
    } while (0)

    float4v acc[4];
    #pragma unroll
    for (int nt = 0; nt < 4; ++nt) acc[nt] = (float4v){0.f, 0.f, 0.f, 0.f};

    // prologue: tiles 0 and 1 in flight
    STAGE(0, As);
    STAGE(1, As + 4096);

    const int row = wid * 16 + m;
    const int hx  = row & 15;

    #pragma unroll
    for (int i = 0; i < 16; ++i) {
        // --- early B-fragment loads for tile i (L2-hot, 8 x 16B).
        // Issued BEFORE this iteration's gload_lds so the compiler's
        // auto-wait at their use is vmcnt(4), not vmcnt(0).
        short8 bfr[2][4];
        #pragma unroll
        for (int s = 0; s < 2; ++s)
            #pragma unroll
            for (int nt = 0; nt < 4; ++nt)
                bfr[s][nt] = *(const short8*)(
                    BT + (size_t)(nt * 16 + m) * 1024 + i * 64 + (s * 4 + q) * 8);
        __builtin_amdgcn_sched_barrier(0);

        __builtin_amdgcn_s_barrier();          // all waves done computing i-1
        if (i + 2 < 16) {
            float* tb_next = As + ((i + 2) % 3) * 4096;
            STAGE(i + 2, tb_next);
        }
        // counted wait: tile i's 4 gloads done; younger stay in flight:
        //   i<14 : gl(i+1)4 + B(i)8 + gl(i+2)4 = 16
        //   i==14: gl(15)4 + B(14)8           = 12
        //   i==15: B(15)8                     = 8
        if (i < 14)       asm volatile("s_waitcnt vmcnt(16)" ::: "memory");
        else if (i == 14) asm volatile("s_waitcnt vmcnt(12)" ::: "memory");
        else              asm volatile("s_waitcnt vmcnt(8)"  ::: "memory");
        __builtin_amdgcn_sched_barrier(0);
        __builtin_amdgcn_s_barrier();          // tile i visible to all waves
        __builtin_amdgcn_sched_barrier(0);

        const float*  tb = As + (i % 3) * 4096;
        const float4* t4 = (const float4*)tb + row * 16;
        #pragma unroll
        for (int s = 0; s < 2; ++s) {
            float4 x0 = t4[(2 * (s * 4 + q))     ^ hx];   // k = s*32+q*8 .. +3
            float4 x1 = t4[(2 * (s * 4 + q) + 1) ^ hx];   // k = .. +4 .. +7
            union { short8 s8; uint32_t u[4]; } P;
            P.u[0] = (uint32_t)f2bf(x0.x) | ((uint32_t)f2bf(x0.y) << 16);
            P.u[1] = (uint32_t)f2bf(x0.z) | ((uint32_t)f2bf(x0.w) << 16);
            P.u[2] = (uint32_t)f2bf(x1.x) | ((uint32_t)f2bf(x1.y) << 16);
            P.u[3] = (uint32_t)f2bf(x1.z) | ((uint32_t)f2bf(x1.w) << 16);
            #pragma unroll
            for (int nt = 0; nt < 4; ++nt)
                acc[nt] = __builtin_amdgcn_mfma_f32_16x16x32_bf16(
                    P.s8, bfr[s][nt], acc[nt], 0, 0, 0);
        }
    }
#undef STAGE

    // epilogue: C/D layout col = lane&15, row = q*4 + reg   [m89/m91 verified]
    #pragma unroll
    for (int reg = 0; reg < 4; ++reg) {
        int grow = blockRow + wid * 16 + q * 4 + reg;
        if (grow < M) {
            #pragma unroll
            for (int nt = 0; nt < 4; ++nt)
                G[(size_t)grow * 64 + nt * 16 + m] = f2bf(acc[nt][reg]);
        }
    }
}

// ---------------------------------------------------------------------------
// Kernel 3: per-edge MLP, MFMA version (round-2, passing).
//   t[64] = relu(g1[src]+g2[dst]+tbias)  -> bf16, staged in LDS (256 edges)
//   U[256][32] = T @ Wm2   via mfma_f32_16x16x32_bf16 (fp32 accum)
//   pred = relu(U + bm2) @ Wm3 + bm3     via 16-lane shfl_xor reduce
// ---------------------------------------------------------------------------
__global__ __launch_bounds__(256) void edge_mlp_kernel(
    const uint16_t* __restrict__ g1, const uint16_t* __restrict__ g2,
    const float* __restrict__ tbias, const int* __restrict__ eidx,
    const uint16_t* __restrict__ Wm2bfT, const float* __restrict__ bm2,
    const float* __restrict__ Wm3, const float* __restrict__ bm3,
    float* __restrict__ out, int E)
{
    __shared__ uint16_t T[256 * 64];   // 32 KB

    const int t    = threadIdx.x;
    const int wid  = t >> 6;
    const int lane = t & 63;
    const int m    = lane & 15;
    const int q    = lane >> 4;

    short8 bfrag[2][2];
    #pragma unroll
    for (int s = 0; s < 2; ++s)
        #pragma unroll
        for (int nt = 0; nt < 2; ++nt)
            bfrag[s][nt] = *(const short8*)(Wm2bfT + (nt * 16 + m) * 64 + s * 32 + q * 8);

    const float bm2a = bm2[m],      bm2b = bm2[16 + m];
    const float w3a  = Wm3[m],      w3b  = Wm3[16 + m];
    const float b3   = bm3[0];

    const int tileBase = blockIdx.x * 256;
    int e = tileBase + t; if (e >= E) e = E - 1;
    const int src = eidx[e];
    const int dst = eidx[E + e];
    const uint4* r1 = (const uint4*)(g1 + (size_t)src * 64);
    const uint4* r2 = (const uint4*)(g2 + (size_t)dst * 64);

    uint4 A[8], B[8];
    #pragma unroll
    for (int c = 0; c < 8; ++c) { A[c] = r1[c]; B[c] = r2[c]; }

    #pragma unroll
    for (int c = 0; c < 8; ++c) {
        uint32_t aw[4] = { A[c].x, A[c].y, A[c].z, A[c].w };
        uint32_t bw[4] = { B[c].x, B[c].y, B[c].z, B[c].w };
        uint32_t pw[4];
        #pragma unroll
        for (int h = 0; h < 4; ++h) {
            float alo, ahi, blo, bhi;
            { union { uint32_t i; float f; } v; v.i = aw[h] << 16;        alo = v.f; }
            { union { uint32_t i; float f; } v; v.i = aw[h] & 0xffff0000u; ahi = v.f; }
            { union { uint32_t i; float f; } v; v.i = bw[h] << 16;        blo = v.f; }
            { union { uint32_t i; float f; } v; v.i = bw[h] & 0xffff0000u; bhi = v.f; }
            float t0 = fmaxf(alo + blo + tbias[c * 8 + 2 * h],     0.f);
            float t1 = fmaxf(ahi + bhi + tbias[c * 8 + 2 * h + 1], 0.f);
            pw[h] = (uint32_t)f2bf(t0) | ((uint32_t)f2bf(t1) << 16);
        }
        uint4 pk; pk.x = pw[0]; pk.y = pw[1]; pk.z = pw[2]; pk.w = pw[3];
        int pc = c ^ (t & 7);
        *(uint4*)(T + t * 64 + pc * 8) = pk;
    }
    __syncthreads();

    float4v acc[4][2];
    #pragma unroll
    for (int r = 0; r < 4; ++r) {
        acc[r][0] = (float4v){0.f, 0.f, 0.f, 0.f};
        acc[r][1] = (float4v){0.f, 0.f, 0.f, 0.f};
    }
    #pragma unroll
    for (int r = 0; r < 4; ++r) {
        const int row = wid * 64 + r * 16 + m;
        #pragma unroll
        for (int s = 0; s < 2; ++s) {
            const int pc = (s * 4 + q) ^ (row & 7);
            short8 af = *(const short8*)(T + row * 64 + pc * 8);
            acc[r][0] = __builtin_amdgcn_mfma_f32_16x16x32_bf16(af, bfrag[s][0], acc[r][0], 0, 0, 0);
            acc[r][1] = __builtin_amdgcn_mfma_f32_16x16x32_bf16(af, bfrag[s][1], acc[r][1], 0, 0, 0);
        }
    }

    #pragma unroll
    for (int r = 0; r < 4; ++r) {
        #pragma unroll
        for (int reg = 0; reg < 4; ++reg) {
            float v0 = fmaxf(acc[r][0][reg] + bm2a, 0.f);
            float v1 = fmaxf(acc[r][1][reg] + bm2b, 0.f);
            float p  = fmaf(v0, w3a, v1 * w3b);
            p += __shfl_xor(p, 1);
            p += __shfl_xor(p, 2);
            p += __shfl_xor(p, 4);
            p += __shfl_xor(p, 8);
            int eo = tileBase + wid * 64 + r * 16 + q * 4 + reg;
            if (m == 0 && eo < E) out[eo] = p + b3;
        }
    }
}

// ---------------------------------------------------------------------------
extern "C" void kernel_launch(void* const* d_in, const int* in_sizes, int n_in,
                              void* d_out, int out_size, void* d_ws, size_t ws_size,
                              hipStream_t stream) {
    const float* x_gene = (const float*)d_in[0];
    const float* x_cell = (const float*)d_in[1];
    const int*   eidx   = (const int*)d_in[2];
    const float* W1  = (const float*)d_in[3];
    const float* b1  = (const float*)d_in[4];
    const float* W2  = (const float*)d_in[5];
    const float* b2  = (const float*)d_in[6];
    const float* Wm1 = (const float*)d_in[7];
    const float* bm1 = (const float*)d_in[8];
    const float* Wm2 = (const float*)d_in[9];
    const float* bm2 = (const float*)d_in[10];
    const float* Wm3 = (const float*)d_in[11];
    const float* bm3 = (const float*)d_in[12];

    const int M1 = in_sizes[0] / 1024;
    const int M2 = in_sizes[1] / 1024;
    const int E  = in_sizes[2] / 2;

    uint8_t* ws = (uint8_t*)d_ws;
    uint16_t* A1T    = (uint16_t*)(ws + 0);          // 131072 B
    uint16_t* A2T    = (uint16_t*)(ws + 131072);     // 131072 B
    float*    tbias  = (float*)(ws + 262144);        //   256 B
    uint16_t* Wm2bfT = (uint16_t*)(ws + 262400);     //  4096 B
    uint16_t* G1     = (uint16_t*)(ws + 524288);
    size_t g1_bytes  = ((size_t)M1 * 64 * 2 + 127) & ~(size_t)127;
    uint16_t* G2     = (uint16_t*)(ws + 524288 + g1_bytes);

    precompute_kernel<<<513, 256, 0, stream>>>(
        W1, W2, Wm1, Wm2, b1, b2, bm1, A1T, A2T, tbias, Wm2bfT);

    int Mmax = M1 > M2 ? M1 : M2;
    dim3 ggrid((Mmax + 63) / 64, 2);
    gemm64_kernel<<<ggrid, 256, 0, stream>>>(x_gene, x_cell, A1T, A2T, G1, G2, M1, M2);

    edge_mlp_kernel<<<(E + 255) / 256, 256, 0, stream>>>(
        G1, G2, tbias, eidx, Wm2bfT, bm2, Wm3, bm3, (float*)d_out, E);
}